// Round 1
// baseline (463.626 us; speedup 1.0000x reference)
//
#include <hip/hip_runtime.h>
#include <stdint.h>

typedef short short8 __attribute__((ext_vector_type(8)));
typedef float floatx4 __attribute__((ext_vector_type(4)));

#define LOG2E 1.44269504088896340736f

static __device__ __forceinline__ unsigned short f2bf(float f) {
  unsigned int u = __float_as_uint(f);
  u += 0x7fffu + ((u >> 16) & 1u);
  return (unsigned short)(u >> 16);
}

static __device__ __forceinline__ float fexp2(float x) {
#if __has_builtin(__builtin_amdgcn_exp2f)
  return __builtin_amdgcn_exp2f(x);
#else
  return exp2f(x);
#endif
}

#define GLD_LDS16(gp, lp)                                                      \
  __builtin_amdgcn_global_load_lds(                                            \
      (const __attribute__((address_space(1))) void*)(gp),                     \
      (__attribute__((address_space(3))) void*)(lp), 16, 0, 0)

// ---------------------------------------------------------------- convert
__global__ __launch_bounds__(256) void cvt_f32_bf16(
    const float* __restrict__ in, unsigned short* __restrict__ out, int n) {
  int i = (blockIdx.x * 256 + threadIdx.x) * 4;
  if (i >= n) return;
  float4 v = *(const float4*)(in + i);
  ushort4 u;
  u.x = f2bf(v.x); u.y = f2bf(v.y); u.z = f2bf(v.z); u.w = f2bf(v.w);
  *(ushort4*)(out + i) = u;
}

// ---------------------------------------------------------------- GEMM
// C[M,N] = A[M,K] @ B[N,K]^T + bias   (A,B bf16 row-major, K contiguous)
// MODE 0: write fp32 C to outF.
// MODE 1: qkv epilogue -> q[B,h,T,d], k[B,h,T,d], vT[B,h,d,T] as bf16.
template <int MODE>
__global__ __launch_bounds__(256, 2) void gemm_bt(
    const unsigned short* __restrict__ A, const unsigned short* __restrict__ Bm,
    const float* __restrict__ bias, float* __restrict__ outF,
    unsigned short* __restrict__ qo, unsigned short* __restrict__ ko,
    unsigned short* __restrict__ vto, int M, int N, int K) {
  __shared__ unsigned short As[128 * 64];
  __shared__ unsigned short Bs[128 * 64];
  const int tid = threadIdx.x;
  const int w = tid >> 6, l = tid & 63;
  const int lr = l & 15, lg = l >> 4;
  const int nbn = N >> 7;
  const int nwg = gridDim.x;
  const int bid = blockIdx.x;
  const int cpx = nwg >> 3;                       // grid % 8 == 0 for all launches
  const int swz = (bid & 7) * cpx + (bid >> 3);   // XCD-aware swizzle (bijective)
  const int bm = swz / nbn, bn = swz % nbn;
  const int wm = w >> 1, wn = w & 1;

  floatx4 acc[4][4];
#pragma unroll
  for (int i = 0; i < 4; ++i)
#pragma unroll
    for (int j = 0; j < 4; ++j) acc[i][j] = (floatx4){0.f, 0.f, 0.f, 0.f};

  for (int k0 = 0; k0 < K; k0 += 64) {
    // stage A tile 128x64 bf16 (16KB = 1024 x 16B chunks), linear LDS
#pragma unroll
    for (int i = 0; i < 4; ++i) {
      int c = i * 256 + tid;
      const unsigned short* ga =
          A + ((size_t)bm * 128 + (c >> 3)) * K + k0 + (c & 7) * 8;
      GLD_LDS16(ga, As + (size_t)(i * 256 + w * 64) * 8);
    }
#pragma unroll
    for (int i = 0; i < 4; ++i) {
      int c = i * 256 + tid;
      const unsigned short* gb =
          Bm + ((size_t)bn * 128 + (c >> 3)) * K + k0 + (c & 7) * 8;
      GLD_LDS16(gb, Bs + (size_t)(i * 256 + w * 64) * 8);
    }
    __syncthreads();
#pragma unroll
    for (int kk = 0; kk < 2; ++kk) {
      short8 af[4], bf[4];
#pragma unroll
      for (int i = 0; i < 4; ++i)
        af[i] = *(const short8*)&As[(wm * 64 + i * 16 + lr) * 64 + kk * 32 + lg * 8];
#pragma unroll
      for (int j = 0; j < 4; ++j)
        bf[j] = *(const short8*)&Bs[(wn * 64 + j * 16 + lr) * 64 + kk * 32 + lg * 8];
#pragma unroll
      for (int i = 0; i < 4; ++i)
#pragma unroll
        for (int j = 0; j < 4; ++j)
          acc[i][j] = __builtin_amdgcn_mfma_f32_16x16x32_bf16(af[i], bf[j],
                                                              acc[i][j], 0, 0, 0);
    }
    __syncthreads();
  }

  // epilogue: C row = (l>>4)*4+reg, col = l&15 within each 16x16 fragment
#pragma unroll
  for (int i = 0; i < 4; ++i) {
    int row0 = bm * 128 + wm * 64 + i * 16 + lg * 4;
#pragma unroll
    for (int j = 0; j < 4; ++j) {
      int col = bn * 128 + wn * 64 + j * 16 + lr;
      float bv = bias[col];
#pragma unroll
      for (int jj = 0; jj < 4; ++jj) {
        float v = acc[i][j][jj] + bv;
        int r = row0 + jj;
        if (MODE == 0) {
          outF[(size_t)r * N + col] = v;
        } else {
          int three = col >> 10, cc = col & 1023;
          int h = cc >> 6, d = cc & 63;
          int b = r >> 11, t = r & 2047;
          unsigned short hv = f2bf(v);
          if (three == 0)
            qo[(((size_t)(b * 16 + h)) * 2048 + t) * 64 + d] = hv;
          else if (three == 1)
            ko[(((size_t)(b * 16 + h)) * 2048 + t) * 64 + d] = hv;
          else
            vto[(((size_t)(b * 16 + h)) * 64 + d) * 2048 + t] = hv;
        }
      }
    }
  }
}

// ---------------------------------------------------------------- attention
// grid: 64 (b,h) x 16 q-tiles; block 256 = 4 waves x 32 q-rows; KVBLK=64
__global__ __launch_bounds__(256, 2) void attn_fwd(
    const unsigned short* __restrict__ Qg, const unsigned short* __restrict__ Kg,
    const unsigned short* __restrict__ VTg, unsigned short* __restrict__ Og) {
  const int bid = blockIdx.x;
  const int bh = bid >> 4, qt = bid & 15;
  const int b = bh >> 4, h = bh & 15;
  const int tid = threadIdx.x, w = tid >> 6, l = tid & 63;
  const int lr = l & 15, lg = l >> 4;
  const unsigned short* Q = Qg + (size_t)bh * (2048 * 64);
  const unsigned short* K = Kg + (size_t)bh * (2048 * 64);
  const unsigned short* VT = VTg + (size_t)bh * (64 * 2048);
  const int q0 = qt * 128 + w * 32;

  __shared__ unsigned short P[4][32][72];  // wave-private, padded (+8) rows

  short8 qf[2][2];
#pragma unroll
  for (int r = 0; r < 2; ++r)
#pragma unroll
    for (int kk = 0; kk < 2; ++kk)
      qf[r][kk] = *(const short8*)&Q[(size_t)(q0 + r * 16 + lr) * 64 + kk * 32 + lg * 8];

  floatx4 o[2][4];
  float m_i[2][4], l_i[2][4];
#pragma unroll
  for (int r = 0; r < 2; ++r) {
#pragma unroll
    for (int f = 0; f < 4; ++f) o[r][f] = (floatx4){0.f, 0.f, 0.f, 0.f};
#pragma unroll
    for (int jj = 0; jj < 4; ++jj) {
      m_i[r][jj] = -__builtin_inff();
      l_i[r][jj] = 0.f;
    }
  }

  for (int t0 = 0; t0 < 2048; t0 += 64) {
    floatx4 s[2][4];
#pragma unroll
    for (int r = 0; r < 2; ++r)
#pragma unroll
      for (int f = 0; f < 4; ++f) s[r][f] = (floatx4){0.f, 0.f, 0.f, 0.f};

    // S = Q @ K^T  (K rows are contiguous-16B B-fragments)
#pragma unroll
    for (int kk = 0; kk < 2; ++kk) {
      short8 kf[4];
#pragma unroll
      for (int f = 0; f < 4; ++f)
        kf[f] = *(const short8*)&K[(size_t)(t0 + f * 16 + lr) * 64 + kk * 32 + lg * 8];
#pragma unroll
      for (int r = 0; r < 2; ++r)
#pragma unroll
        for (int f = 0; f < 4; ++f)
          s[r][f] = __builtin_amdgcn_mfma_f32_16x16x32_bf16(qf[r][kk], kf[f],
                                                            s[r][f], 0, 0, 0);
    }

    // scale + per-row max (row lives in a 16-lane group; cols = l&15 x 4 frags)
    float mt[2][4];
#pragma unroll
    for (int r = 0; r < 2; ++r)
#pragma unroll
      for (int jj = 0; jj < 4; ++jj) {
#pragma unroll
        for (int f = 0; f < 4; ++f) s[r][f][jj] *= 0.125f;
        mt[r][jj] = fmaxf(fmaxf(s[r][0][jj], s[r][1][jj]),
                          fmaxf(s[r][2][jj], s[r][3][jj]));
      }
#pragma unroll
    for (int mask = 1; mask <= 8; mask <<= 1)
#pragma unroll
      for (int r = 0; r < 2; ++r)
#pragma unroll
        for (int jj = 0; jj < 4; ++jj)
          mt[r][jj] = fmaxf(mt[r][jj], __shfl_xor(mt[r][jj], mask));

    float al[2][4], rs[2][4];
#pragma unroll
    for (int r = 0; r < 2; ++r)
#pragma unroll
      for (int jj = 0; jj < 4; ++jj) {
        float mn = fmaxf(m_i[r][jj], mt[r][jj]);
        al[r][jj] = fexp2((m_i[r][jj] - mn) * LOG2E);
        m_i[r][jj] = mn;
        rs[r][jj] = 0.f;
      }

    // P = exp(S - m), write to LDS in C-layout, sum rows
#pragma unroll
    for (int r = 0; r < 2; ++r)
#pragma unroll
      for (int f = 0; f < 4; ++f)
#pragma unroll
        for (int jj = 0; jj < 4; ++jj) {
          float pv = fexp2((s[r][f][jj] - m_i[r][jj]) * LOG2E);
          rs[r][jj] += pv;
          P[w][r * 16 + lg * 4 + jj][f * 16 + lr] = f2bf(pv);
        }
#pragma unroll
    for (int mask = 1; mask <= 8; mask <<= 1)
#pragma unroll
      for (int r = 0; r < 2; ++r)
#pragma unroll
        for (int jj = 0; jj < 4; ++jj)
          rs[r][jj] += __shfl_xor(rs[r][jj], mask);
#pragma unroll
    for (int r = 0; r < 2; ++r)
#pragma unroll
      for (int jj = 0; jj < 4; ++jj)
        l_i[r][jj] = l_i[r][jj] * al[r][jj] + rs[r][jj];

    // rescale O
#pragma unroll
    for (int r = 0; r < 2; ++r)
#pragma unroll
      for (int f = 0; f < 4; ++f)
#pragma unroll
        for (int jj = 0; jj < 4; ++jj) o[r][f][jj] *= al[r][jj];

    __builtin_amdgcn_wave_barrier();
    asm volatile("" ::: "memory");  // order LDS write -> read (in-wave DS is in-order)

    // O += P @ V   (A-frags from LDS, B-frags contiguous from V^T)
#pragma unroll
    for (int kk = 0; kk < 2; ++kk) {
      short8 pa[2];
#pragma unroll
      for (int r = 0; r < 2; ++r)
        pa[r] = *(const short8*)&P[w][r * 16 + lr][kk * 32 + lg * 8];
#pragma unroll
      for (int f = 0; f < 4; ++f) {
        short8 vf =
            *(const short8*)&VT[(size_t)(f * 16 + lr) * 2048 + t0 + kk * 32 + lg * 8];
#pragma unroll
        for (int r = 0; r < 2; ++r)
          o[r][f] = __builtin_amdgcn_mfma_f32_16x16x32_bf16(pa[r], vf, o[r][f], 0, 0, 0);
      }
    }
    __builtin_amdgcn_wave_barrier();
    asm volatile("" ::: "memory");
  }

  // epilogue: out[b, t, h*64+d] bf16
#pragma unroll
  for (int r = 0; r < 2; ++r)
#pragma unroll
    for (int jj = 0; jj < 4; ++jj) {
      float inv = 1.f / l_i[r][jj];
      int row = q0 + r * 16 + lg * 4 + jj;
#pragma unroll
      for (int f = 0; f < 4; ++f) {
        int col = h * 64 + f * 16 + lr;
        Og[((size_t)b * 2048 + row) * 1024 + col] = f2bf(o[r][f][jj] * inv);
      }
    }
}

// ---------------------------------------------------------------- launch
extern "C" void kernel_launch(void* const* d_in, const int* in_sizes, int n_in,
                              void* d_out, int out_size, void* d_ws, size_t ws_size,
                              hipStream_t stream) {
  const float* x = (const float*)d_in[0];
  const float* w_qkv = (const float*)d_in[1];
  const float* b_qkv = (const float*)d_in[2];
  const float* w_proj = (const float*)d_in[3];
  const float* b_proj = (const float*)d_in[4];
  float* out = (float*)d_out;

  char* p = (char*)d_ws;
  unsigned short* xb = (unsigned short*)p;     p += (size_t)8192 * 1024 * 2;
  unsigned short* wqkvb = (unsigned short*)p;  p += (size_t)3072 * 1024 * 2;
  unsigned short* wprojb = (unsigned short*)p; p += (size_t)1024 * 1024 * 2;
  unsigned short* qb = (unsigned short*)p;     p += (size_t)64 * 2048 * 64 * 2;
  unsigned short* kb = (unsigned short*)p;     p += (size_t)64 * 2048 * 64 * 2;
  unsigned short* vtb = (unsigned short*)p;    p += (size_t)64 * 64 * 2048 * 2;
  unsigned short* attnb = (unsigned short*)p;  p += (size_t)8192 * 1024 * 2;

  cvt_f32_bf16<<<dim3(8192), dim3(256), 0, stream>>>(x, xb, 8192 * 1024);
  cvt_f32_bf16<<<dim3(3072), dim3(256), 0, stream>>>(w_qkv, wqkvb, 3072 * 1024);
  cvt_f32_bf16<<<dim3(1024), dim3(256), 0, stream>>>(w_proj, wprojb, 1024 * 1024);

  gemm_bt<1><<<dim3(64 * 24), dim3(256), 0, stream>>>(
      xb, wqkvb, b_qkv, nullptr, qb, kb, vtb, 8192, 3072, 1024);

  attn_fwd<<<dim3(64 * 16), dim3(256), 0, stream>>>(qb, kb, vtb, attnb);

  gemm_bt<0><<<dim3(64 * 8), dim3(256), 0, stream>>>(
      attnb, wprojb, b_proj, out, nullptr, nullptr, nullptr, 8192, 1024, 1024);
}